// Round 3
// baseline (340.405 us; speedup 1.0000x reference)
//
#include <hip/hip_runtime.h>
#include <cstdint>
#include <cstddef>

#define MDIM 4096   // batch
#define NDIM 4096   // out features
#define KDIM 4096   // in features

typedef _Float16 half8  __attribute__((ext_vector_type(8)));
typedef float    floatx4 __attribute__((ext_vector_type(4)));

// Hamilton product tables: out_comp = sum_c sign[comp][c] * (x_c @ W_{q[comp][c]}^T)
__device__ __constant__ int   d_qtab[16] = {0,1,2,3,  1,0,3,2,  2,3,0,1,  3,2,1,0};
__device__ __constant__ float d_stab[16] = {1.f,-1.f,-1.f,-1.f,
                                            1.f, 1.f, 1.f,-1.f,
                                            1.f,-1.f, 1.f, 1.f,
                                            1.f, 1.f,-1.f, 1.f};

// ---------------- pre-pass: W fp32 -> fp16 cast ----------------
// cast the four 1024x1024 W matrices fp32 -> fp16 into one [4][1024][1024] buffer
__global__ void cast_w_kernel(const float* __restrict__ W0, const float* __restrict__ W1,
                              const float* __restrict__ W2, const float* __restrict__ W3,
                              _Float16* __restrict__ Wh) {
    int idx = blockIdx.x * 256 + threadIdx.x;          // 0 .. 512K-1
    int e = idx << 3;                                   // element index, 0..4M-1
    int m = e >> 20;                                    // which matrix
    const float* Ws[4] = {W0, W1, W2, W3};
    const float* src = Ws[m] + (e & ((1 << 20) - 1));
    float4 a = *(const float4*)src;
    float4 b = *(const float4*)(src + 4);
    half8 h = {(_Float16)a.x, (_Float16)a.y, (_Float16)a.z, (_Float16)a.w,
               (_Float16)b.x, (_Float16)b.y, (_Float16)b.z, (_Float16)b.w};
    *(half8*)(Wh + e) = h;
}

// ---------------- MFMA GEMM with fused A-cast ----------------
// C[M,N] = x[M,K](fp32, cast in-staging) * W_big[N,K]^T + bias[N].
// W_big rows come straight from the four fp16 W matrices; the wave-uniform
// sign s[comp][c] is applied to the A fragments. fp32 accumulate.
// Block: 256 threads (4 waves), tile 128x128, BK=32, single-buffered LDS.

__device__ __forceinline__ void gload_lds16(const _Float16* g, _Float16* l) {
    __builtin_amdgcn_global_load_lds(
        (const __attribute__((address_space(1))) unsigned int*)g,
        (__attribute__((address_space(3))) unsigned int*)l,
        16, 0, 0);
}

__global__ __launch_bounds__(256, 4) void gemm_kernel(
        const float* __restrict__ X,         // [4096,4096] fp32 (raw input)
        const _Float16* __restrict__ Wh,     // [4][1024][1024] fp16
        const float* __restrict__ b0, const float* __restrict__ b1,
        const float* __restrict__ b2, const float* __restrict__ b3,
        float* __restrict__ C) {
    __shared__ _Float16 As[128 * 32];   // 8 KB
    __shared__ _Float16 Bs[128 * 32];   // 8 KB

    const int tid  = threadIdx.x;
    const int lane = tid & 63;
    const int wave = tid >> 6;
    const int wm = (wave & 1) * 64;
    const int wn = (wave >> 1) * 64;

    // L2-friendly swizzle: 8 m-tiles per supergroup, n advances inside
    const int g = blockIdx.x;                 // 0..1023 over 32x32 tiles
    const int group_id = g >> 8;              // 0..3
    const int bm = group_id * 8 + (g & 7);
    const int bn = (g & 255) >> 3;
    const int m0 = bm * 128;
    const int n0 = bn * 128;
    const int comp = n0 >> 10;                // output quaternion component (block-uniform)

    // staging geometry: 4 threads per row, 16B (8 halves) chunks
    const int srow = tid >> 2;                // 0..63
    const int q_ld = tid & 3;                 // logical k-chunk this thread stages
    const int swz  = (srow >> 1) & 3;         // row-pair swizzle (same for srow+64)
    const int wpos = q_ld ^ swz;              // LDS chunk position for A ds_write

    // A: fp32 global read (unswizzled chunk), manual cvt + swizzled ds_write
    const float* Xg = X + (size_t)(m0 + srow) * KDIM + q_ld * 8;
    _Float16* Awr0 = As + srow * 32 + wpos * 8;
    _Float16* Awr1 = As + (srow + 64) * 32 + wpos * 8;

    // B: fp16 DMA (LDS slot forced to tid*8) -> swizzle the GLOBAL chunk
    const int skc  = (q_ld ^ swz) * 8;
    const int brow = (n0 & 1023) + srow;      // row within the 1024-row W matrix
    _Float16* Bsl0 = Bs + tid * 8;
    _Float16* Bsl1 = Bs + 2048 + tid * 8;

    floatx4 acc[4][4];
#pragma unroll
    for (int i = 0; i < 4; i++)
#pragma unroll
        for (int j = 0; j < 4; j++)
            acc[i][j] = (floatx4){0.f, 0.f, 0.f, 0.f};

    const int fr = lane & 15;                 // row (A) / col (B) within 16
    const int qf = lane >> 4;                 // k-chunk 0..3
    const int slot8 = (qf ^ ((fr >> 1) & 3)) * 8;   // swizzled LDS chunk offset

    for (int c = 0; c < 4; c++) {
        const int t = comp * 4 + c;
        const _Float16* Bg0 = Wh + ((size_t)d_qtab[t] << 20) + (size_t)brow * 1024 + skc;
        const float*    Ag  = Xg + c * 1024;
        const _Float16 s = (_Float16)d_stab[t];
        half8 sv = {s, s, s, s, s, s, s, s};

        for (int kk = 0; kk < 1024; kk += 32) {
            // B-tile via LDS-DMA
            gload_lds16(Bg0 + kk, Bsl0);
            gload_lds16(Bg0 + (size_t)64 * 1024 + kk, Bsl1);
            // A-tile: fp32 load + cvt + ds_write (rows srow and srow+64)
            floatx4 a0 = *(const floatx4*)(Ag + kk);
            floatx4 a1 = *(const floatx4*)(Ag + kk + 4);
            floatx4 a2 = *(const floatx4*)(Ag + (size_t)64 * KDIM + kk);
            floatx4 a3 = *(const floatx4*)(Ag + (size_t)64 * KDIM + kk + 4);
            half8 h0 = {(_Float16)a0.x, (_Float16)a0.y, (_Float16)a0.z, (_Float16)a0.w,
                        (_Float16)a1.x, (_Float16)a1.y, (_Float16)a1.z, (_Float16)a1.w};
            half8 h1 = {(_Float16)a2.x, (_Float16)a2.y, (_Float16)a2.z, (_Float16)a2.w,
                        (_Float16)a3.x, (_Float16)a3.y, (_Float16)a3.z, (_Float16)a3.w};
            *(half8*)Awr0 = h0;
            *(half8*)Awr1 = h1;
            __syncthreads();              // drains ds_write (lgkm) + DMA (vmcnt)

            half8 af[4], bf[4];
#pragma unroll
            for (int i = 0; i < 4; i++) {
                af[i] = *(const half8*)(As + (wm + i * 16 + fr) * 32 + slot8) * sv;
                bf[i] = *(const half8*)(Bs + (wn + i * 16 + fr) * 32 + slot8);
            }
#pragma unroll
            for (int i = 0; i < 4; i++)
#pragma unroll
                for (int j = 0; j < 4; j++)
                    acc[i][j] = __builtin_amdgcn_mfma_f32_16x16x32_f16(af[i], bf[j], acc[i][j], 0, 0, 0);

            __syncthreads();
        }
    }

    // Epilogue: D[row][col], col = lane&15, row = (lane>>4)*4 + r  [m89 layout]
    const int col   = lane & 15;
    const int rquad = (lane >> 4) * 4;
    const float* bs[4] = {b0, b1, b2, b3};
#pragma unroll
    for (int j = 0; j < 4; j++) {
        const int gn = n0 + wn + j * 16 + col;
        const int o  = gn & 1023;
        float bv = 0.f;
#pragma unroll
        for (int c = 0; c < 4; c++)
            bv += d_stab[comp * 4 + c] * bs[d_qtab[comp * 4 + c]][o];
#pragma unroll
        for (int i = 0; i < 4; i++) {
            const int gmb = m0 + wm + i * 16 + rquad;
#pragma unroll
            for (int r = 0; r < 4; r++)
                C[(size_t)(gmb + r) * NDIM + gn] = acc[i][j][r] + bv;
        }
    }
}

// ---------------- fp32 fallback (only if ws too small) ----------------
__global__ void fallback_kernel(const float* __restrict__ x,
                                const float* __restrict__ W0, const float* __restrict__ W1,
                                const float* __restrict__ W2, const float* __restrict__ W3,
                                const float* __restrict__ b0, const float* __restrict__ b1,
                                const float* __restrict__ b2, const float* __restrict__ b3,
                                float* __restrict__ out) {
    int idx = blockIdx.x * 256 + threadIdx.x;   // 16M outputs
    int m = idx >> 12, n = idx & 4095;
    int comp = n >> 10, o = n & 1023;
    const float* Ws[4] = {W0, W1, W2, W3};
    const float* bs[4] = {b0, b1, b2, b3};
    float acc = 0.f;
    for (int c = 0; c < 4; c++) {
        int t = comp * 4 + c;
        const float* wr = Ws[d_qtab[t]] + (size_t)o * 1024;
        const float* xr = x + (size_t)m * 4096 + c * 1024;
        float s = d_stab[t];
        float dot = 0.f;
        for (int i = 0; i < 1024; i += 4) {
            float4 wv = *(const float4*)(wr + i);
            float4 xv = *(const float4*)(xr + i);
            dot += wv.x * xv.x + wv.y * xv.y + wv.z * xv.z + wv.w * xv.w;
        }
        acc += s * dot + s * bs[d_qtab[t]][o];
    }
    out[idx] = acc;
}

// ---------------- launch ----------------
extern "C" void kernel_launch(void* const* d_in, const int* in_sizes, int n_in,
                              void* d_out, int out_size, void* d_ws, size_t ws_size,
                              hipStream_t stream) {
    const float* x = (const float*)d_in[0];
    const float* W[4];
    const float* b[4];
    int wi = 0, bi = 0;
    for (int i = 1; i < n_in && i < 9; i++) {
        if (in_sizes[i] > 4096) { if (wi < 4) W[wi++] = (const float*)d_in[i]; }
        else                    { if (bi < 4) b[bi++] = (const float*)d_in[i]; }
    }
    float* out = (float*)d_out;

    const size_t wh_elems = (size_t)4 * 1024 * 1024;    // 4M fp16 = 8 MB
    const size_t needed = wh_elems * 2;

    if (ws_size < needed) {
        fallback_kernel<<<(MDIM * NDIM) / 256, 256, 0, stream>>>(
            x, W[0], W[1], W[2], W[3], b[0], b[1], b[2], b[3], out);
        return;
    }

    _Float16* Wh = (_Float16*)d_ws;

    cast_w_kernel<<<(4 * 1024 * 1024) / (256 * 8), 256, 0, stream>>>(W[0], W[1], W[2], W[3], Wh);
    gemm_kernel<<<(MDIM / 128) * (NDIM / 128), 256, 0, stream>>>(
        x, Wh, b[0], b[1], b[2], b[3], out);
}